// Round 5
// baseline (506.880 us; speedup 1.0000x reference)
//
#include <hip/hip_runtime.h>
#include <hip/hip_bf16.h>
#include <stdint.h>

typedef int v4i __attribute__((ext_vector_type(4)));

#define GM 4096
#define GN 16384
#define GK 4096
#define BM 256
#define BN 256
#define BK 128            // i8 elements == bytes per K-step
#define NTILES (GK / BK)  // 32

__device__ __forceinline__ void gload16(const void* g, void* l) {
  __builtin_amdgcn_global_load_lds(
      (const __attribute__((address_space(1))) void*)g,
      (__attribute__((address_space(3))) void*)l, 16, 0, 0);
}

// ---------------- per-row dynamic quantization (x f32 -> int8 + scale) ----------------
__global__ __launch_bounds__(256) void quant_rows(
    const float* __restrict__ x, int8_t* __restrict__ xq,
    float* __restrict__ xs, int K) {
  const int row = blockIdx.x;
  const int t = threadIdx.x;
  const float4* src = (const float4*)(x + (size_t)row * K) + t * 4;
  float4 v[4];
  float m = 0.f;
#pragma unroll
  for (int i = 0; i < 4; ++i) {
    v[i] = src[i];
    m = fmaxf(m, fmaxf(fmaxf(fabsf(v[i].x), fabsf(v[i].y)),
                       fmaxf(fabsf(v[i].z), fabsf(v[i].w))));
  }
#pragma unroll
  for (int off = 1; off < 64; off <<= 1)
    m = fmaxf(m, __shfl_xor(m, off, 64));
  __shared__ float wmax[4];
  if ((t & 63) == 0) wmax[t >> 6] = m;
  __syncthreads();
  const float gm = fmaxf(fmaxf(wmax[0], wmax[1]), fmaxf(wmax[2], wmax[3]));
  const float scale = (gm + 1e-5f) / 127.0f;  // == ref x_scales
  if (t == 0) xs[row] = scale;
  unsigned packed[4];
#pragma unroll
  for (int i = 0; i < 4; ++i) {
    float fv[4] = {v[i].x, v[i].y, v[i].z, v[i].w};
    unsigned p = 0;
#pragma unroll
    for (int j = 0; j < 4; ++j) {
      int q = (int)rintf(fv[j] / scale);  // RNE, matches np.round
      q = max(-128, min(127, q));
      p |= (unsigned)(q & 0xff) << (8 * j);
    }
    packed[i] = p;
  }
  *(int4*)(xq + (size_t)row * K + t * 16) =
      make_int4((int)packed[0], (int)packed[1], (int)packed[2], (int)packed[3]);
}

// ---------------- W int32 [K][N] -> Wt int8 [N][K] (transpose + pack) ----------------
__global__ __launch_bounds__(256) void transpose_pack(
    const int* __restrict__ W32, int8_t* __restrict__ Wt, int K, int N) {
  __shared__ __align__(16) int8_t tile[64][80];
  const int t = threadIdx.x;
  const int n0 = blockIdx.x * 64;
  const int k0 = blockIdx.y * 64;
  const int ln = t & 63;
  const int wv = t >> 6;
#pragma unroll
  for (int it = 0; it < 16; ++it) {
    const int kk = wv * 16 + it;
    tile[ln][kk] = (int8_t)W32[(size_t)(k0 + kk) * N + n0 + ln];
  }
  __syncthreads();
  const int kb = wv * 16;
  const int4 v = *(const int4*)&tile[ln][kb];
  *(int4*)(Wt + (size_t)(n0 + ln) * K + k0 + kb) = v;
}

// ---------------- int8 GEMM: 256x256 tile, counted-lgkm pipelined schedule -------------
// LDS chunk swizzle: logical (row r, 16B-chunk c) stored at chunk c^(r&7);
// global_load_lds writes linearly -> source pre-swizzled (rule #21).
__global__ __launch_bounds__(512, 2) void gemm_i8(
    const int8_t* __restrict__ Xq, const int8_t* __restrict__ Wt,
    const float* __restrict__ xs, const float* __restrict__ wsc,
    const float* __restrict__ bias, float* __restrict__ C) {
  __shared__ __align__(16) int8_t lA[2][BM][BK];  // 64 KB
  __shared__ __align__(16) int8_t lB[2][BN][BK];  // 64 KB

  const int t = threadIdx.x;
  const int lane = t & 63;
  const int w = t >> 6;
  const int wr = w >> 2;  // 0..1 (M half)
  const int wc = w & 3;   // 0..3 (N quarter)
  const int fr = lane & 15;
  const int kg = lane >> 4;

  // bijective XCD swizzle: 1024 blocks = 8 XCD x (16 M x 8 N) rectangles
  const int bid = blockIdx.x;
  const int xcd = bid & 7;
  const int q = bid >> 3;
  const int tm = q & 15;
  const int tn = xcd * 8 + (q >> 4);
  const size_t rowA0 = (size_t)tm * BM;
  const size_t rowB0 = (size_t)tn * BN;

  // staging: tile = 2048 16B-slots; slot=(i*8+w)*64+lane; r=slot>>3;
  // stored chunk sc=slot&7 holds logical chunk c=sc^(r&7).
  const int8_t* XqB = Xq + rowA0 * GK;
  const int8_t* WtB = Wt + rowB0 * GK;
  int srcOff[4], dstOff[4];
#pragma unroll
  for (int i = 0; i < 4; ++i) {
    const int slot0 = (i * 8 + w) * 64;
    const int slot = slot0 + lane;
    const int r = slot >> 3;
    const int c = (slot & 7) ^ (r & 7);
    srcOff[i] = r * GK + c * 16;
    dstOff[i] = slot0 * 16;  // wave-uniform LDS base
  }

#define STAGE(KT, D)                                                        \
  {                                                                         \
    const int ko = (KT)*BK;                                                 \
    _Pragma("unroll") for (int i = 0; i < 4; ++i)                           \
        gload16(XqB + srcOff[i] + ko, (int8_t*)&lA[(D)][0][0] + dstOff[i]); \
    _Pragma("unroll") for (int i = 0; i < 4; ++i)                           \
        gload16(WtB + srcOff[i] + ko, (int8_t*)&lB[(D)][0][0] + dstOff[i]); \
  }

  // swizzled byte columns for k-slice 0/1
  const int ck0 = ((0 + kg) ^ (fr & 7)) * 16;
  const int ck1 = ((4 + kg) ^ (fr & 7)) * 16;

  v4i acc[8][4] = {};
  v4i areg[4][2], aregh[4][2], breg[4][2];

#define ISSUE_A_LO(D)                                                \
  _Pragma("unroll") for (int mi = 0; mi < 4; ++mi) {                 \
    const int8_t* p = &lA[(D)][wr * 128 + mi * 16 + fr][0];          \
    areg[mi][0] = *(const v4i*)(p + ck0);                            \
    areg[mi][1] = *(const v4i*)(p + ck1);                            \
  }
#define ISSUE_A_HI(D)                                                \
  _Pragma("unroll") for (int mi = 0; mi < 4; ++mi) {                 \
    const int8_t* p = &lA[(D)][wr * 128 + 64 + mi * 16 + fr][0];     \
    aregh[mi][0] = *(const v4i*)(p + ck0);                           \
    aregh[mi][1] = *(const v4i*)(p + ck1);                           \
  }
#define ISSUE_B(NJ, D)                                               \
  {                                                                  \
    const int8_t* p = &lB[(D)][wc * 64 + (NJ)*16 + fr][0];           \
    breg[NJ][0] = *(const v4i*)(p + ck0);                            \
    breg[NJ][1] = *(const v4i*)(p + ck1);                            \
  }

#define MFMA_Q(AR, MI0, NJ0)                                                    \
  _Pragma("unroll") for (int mi = 0; mi < 4; ++mi)                              \
      _Pragma("unroll") for (int nj = 0; nj < 2; ++nj) {                        \
    acc[(MI0) + mi][(NJ0) + nj] = __builtin_amdgcn_mfma_i32_16x16x64_i8(        \
        AR[mi][0], breg[(NJ0) + nj][0], acc[(MI0) + mi][(NJ0) + nj], 0, 0, 0);  \
    acc[(MI0) + mi][(NJ0) + nj] = __builtin_amdgcn_mfma_i32_16x16x64_i8(        \
        AR[mi][1], breg[(NJ0) + nj][1], acc[(MI0) + mi][(NJ0) + nj], 0, 0, 0);  \
  }

  // prologue: stage tiles 0,1; wait tile 0; read-ahead A-lo of tile 0
  STAGE(0, 0);
  STAGE(1, 1);
  asm volatile("s_waitcnt vmcnt(8)" ::: "memory");
  __builtin_amdgcn_s_barrier();
  ISSUE_A_LO(0);

  for (int kt = 0; kt < NTILES; ++kt) {
    const int d = kt & 1;
    // epoch A: issue remaining 16 reads of buf d, MFMA under counted waits
    ISSUE_B(0, d);
    ISSUE_B(1, d);
    ISSUE_B(2, d);
    ISSUE_B(3, d);
    ISSUE_A_HI(d);
    asm volatile("s_waitcnt lgkmcnt(12)" ::: "memory");  // A-lo + B0,B1 done
    __builtin_amdgcn_sched_barrier(0);
    __builtin_amdgcn_s_setprio(1);
    MFMA_Q(areg, 0, 0);
    __builtin_amdgcn_s_setprio(0);
    asm volatile("s_waitcnt lgkmcnt(8)" ::: "memory");  // + B2,B3 done
    __builtin_amdgcn_sched_barrier(0);
    __builtin_amdgcn_s_setprio(1);
    MFMA_Q(areg, 0, 2);
    __builtin_amdgcn_s_setprio(0);
    asm volatile("s_waitcnt lgkmcnt(0)" ::: "memory");  // all reads of buf d done
    __builtin_amdgcn_sched_barrier(0);
    __builtin_amdgcn_s_barrier();  // CU-wide: buf d free to overwrite
    // epoch B: stage kt+2 into d; prove kt+1 landed; read-ahead + trailing MFMA
    if (kt + 2 < NTILES) {
      STAGE(kt + 2, d);
      asm volatile("s_waitcnt vmcnt(8)" ::: "memory");  // tile kt+1 landed
    } else {
      asm volatile("s_waitcnt vmcnt(0)" ::: "memory");  // tail drain
    }
    __builtin_amdgcn_s_barrier();  // CU-wide: buf d^1 valid
    if (kt + 1 < NTILES) { ISSUE_A_LO(d ^ 1); }  // next tile's A-lo flies...
    __builtin_amdgcn_sched_barrier(0);           // ...under these 32 MFMAs
    __builtin_amdgcn_s_setprio(1);
    MFMA_Q(aregh, 4, 0);
    MFMA_Q(aregh, 4, 2);
    __builtin_amdgcn_s_setprio(0);
  }

  // epilogue: dequant + bias -> bf16-round -> f32 store
  // C/D frag: col=lane&15, row=(lane>>4)*4+reg
  float xsv[8][4];
#pragma unroll
  for (int mi = 0; mi < 8; ++mi)
#pragma unroll
    for (int r = 0; r < 4; ++r)
      xsv[mi][r] = xs[rowA0 + wr * 128 + mi * 16 + kg * 4 + r];
#pragma unroll
  for (int nj = 0; nj < 4; ++nj) {
    const int col_l = wc * 64 + nj * 16 + fr;
    const float wsv = wsc[rowB0 + col_l];
    const float bv = bias[rowB0 + col_l];
#pragma unroll
    for (int mi = 0; mi < 8; ++mi) {
#pragma unroll
      for (int r = 0; r < 4; ++r) {
        const size_t row = rowA0 + wr * 128 + mi * 16 + kg * 4 + r;
        const float f = (float)acc[mi][nj][r] * xsv[mi][r] * wsv + bv;
        C[row * GN + rowB0 + col_l] = __bfloat162float(__float2bfloat16(f));
      }
    }
  }
}

extern "C" void kernel_launch(void* const* d_in, const int* in_sizes, int n_in,
                              void* d_out, int out_size, void* d_ws, size_t ws_size,
                              hipStream_t stream) {
  const int M = GM, K = GK, N = GN;
  const float* x = (const float*)d_in[0];
  const int* W32 = (const int*)d_in[1];  // harness pushes integer inputs as int32
  const float* wsc = (const float*)d_in[2];
  const float* bias = (const float*)d_in[3];
  float* out = (float*)d_out;  // reference output dtype is float32 (bf16-rounded)

  // workspace layout: xs (16KB) | Xq (16MB) | Wt (64MB)
  float* xs = (float*)d_ws;
  int8_t* Xq = (int8_t*)d_ws + 16384;
  int8_t* Wt = (int8_t*)d_ws + 16384 + (size_t)M * K;

  transpose_pack<<<dim3(N / 64, K / 64), 256, 0, stream>>>(W32, Wt, K, N);
  quant_rows<<<M, 256, 0, stream>>>(x, Xq, xs, K);
  gemm_i8<<<dim3((M / BM) * (N / BN)), 512, 0, stream>>>(Xq, Wt, xs, wsc, bias,
                                                         out);
}

// Round 6
// 486.656 us; speedup vs baseline: 1.0416x; 1.0416x over previous
//
#include <hip/hip_runtime.h>
#include <hip/hip_bf16.h>
#include <stdint.h>

typedef int v4i __attribute__((ext_vector_type(4)));
typedef int v16i __attribute__((ext_vector_type(16)));

#define GM 4096
#define GN 16384
#define GK 4096
#define BM 256
#define BN 256
#define BK 128            // i8 bytes per K-step
#define NTILES (GK / BK)  // 32

__device__ __forceinline__ void gload16(const void* g, void* l) {
  __builtin_amdgcn_global_load_lds(
      (const __attribute__((address_space(1))) void*)g,
      (__attribute__((address_space(3))) void*)l, 16, 0, 0);
}

// ---------------- per-row dynamic quantization (x f32 -> int8 + scale) ----------------
__global__ __launch_bounds__(256) void quant_rows(
    const float* __restrict__ x, int8_t* __restrict__ xq,
    float* __restrict__ xs, int K) {
  const int row = blockIdx.x;
  const int t = threadIdx.x;
  const float4* src = (const float4*)(x + (size_t)row * K) + t * 4;
  float4 v[4];
  float m = 0.f;
#pragma unroll
  for (int i = 0; i < 4; ++i) {
    v[i] = src[i];
    m = fmaxf(m, fmaxf(fmaxf(fabsf(v[i].x), fabsf(v[i].y)),
                       fmaxf(fabsf(v[i].z), fabsf(v[i].w))));
  }
#pragma unroll
  for (int off = 1; off < 64; off <<= 1)
    m = fmaxf(m, __shfl_xor(m, off, 64));
  __shared__ float wmax[4];
  if ((t & 63) == 0) wmax[t >> 6] = m;
  __syncthreads();
  const float gm = fmaxf(fmaxf(wmax[0], wmax[1]), fmaxf(wmax[2], wmax[3]));
  const float scale = (gm + 1e-5f) / 127.0f;  // == ref x_scales
  if (t == 0) xs[row] = scale;
  unsigned packed[4];
#pragma unroll
  for (int i = 0; i < 4; ++i) {
    float fv[4] = {v[i].x, v[i].y, v[i].z, v[i].w};
    unsigned p = 0;
#pragma unroll
    for (int j = 0; j < 4; ++j) {
      int q = (int)rintf(fv[j] / scale);  // RNE, matches np.round
      q = max(-128, min(127, q));
      p |= (unsigned)(q & 0xff) << (8 * j);
    }
    packed[i] = p;
  }
  *(int4*)(xq + (size_t)row * K + t * 16) =
      make_int4((int)packed[0], (int)packed[1], (int)packed[2], (int)packed[3]);
}

// ---------------- W int32 [K][N] -> Wt int8 [N][K] (transpose + pack) ----------------
__global__ __launch_bounds__(256) void transpose_pack(
    const int* __restrict__ W32, int8_t* __restrict__ Wt, int K, int N) {
  __shared__ __align__(16) int8_t tile[64][80];
  const int t = threadIdx.x;
  const int n0 = blockIdx.x * 64;
  const int k0 = blockIdx.y * 64;
  const int ln = t & 63;
  const int wv = t >> 6;
#pragma unroll
  for (int it = 0; it < 16; ++it) {
    const int kk = wv * 16 + it;
    tile[ln][kk] = (int8_t)W32[(size_t)(k0 + kk) * N + n0 + ln];
  }
  __syncthreads();
  const int kb = wv * 16;
  const int4 v = *(const int4*)&tile[ln][kb];
  *(int4*)(Wt + (size_t)(n0 + ln) * K + k0 + kb) = v;
}

// ---------------- int8 GEMM: 256x256, 32x32x32 MFMA, 1-barrier self-paced tile ---------
// LDS chunk swizzle: logical (row r, 16B-chunk c) stored at chunk c^(r&7);
// global_load_lds writes linearly -> source pre-swizzled (rule #21).
__global__ __launch_bounds__(512, 2) void gemm_i8(
    const int8_t* __restrict__ Xq, const int8_t* __restrict__ Wt,
    const float* __restrict__ xs, const float* __restrict__ wsc,
    const float* __restrict__ bias, float* __restrict__ C) {
  __shared__ __align__(16) int8_t lA[2][BM][BK];  // 64 KB
  __shared__ __align__(16) int8_t lB[2][BN][BK];  // 64 KB

  const int t = threadIdx.x;
  const int lane = t & 63;
  const int w = t >> 6;
  const int wr = w >> 2;      // 0..1 (M half)
  const int wc = w & 3;       // 0..3 (N quarter)
  const int l31 = lane & 31;  // fragment row (A) / col (B)
  const int kg2 = lane >> 5;  // k half-group

  // bijective XCD swizzle: 1024 blocks = 8 XCD x (16 M x 8 N) rectangles
  const int bid = blockIdx.x;
  const int xcd = bid & 7;
  const int q = bid >> 3;
  const int tm = q & 15;
  const int tn = xcd * 8 + (q >> 4);
  const size_t rowA0 = (size_t)tm * BM;
  const size_t rowB0 = (size_t)tn * BN;

  // staging: tile = 2048 16B-slots; slot=(i*8+w)*64+lane; r=slot>>3;
  // stored chunk sc=slot&7 holds logical chunk c=sc^(r&7).
  const int8_t* XqB = Xq + rowA0 * GK;
  const int8_t* WtB = Wt + rowB0 * GK;
  int srcOff[4], dstOff[4];
#pragma unroll
  for (int i = 0; i < 4; ++i) {
    const int slot0 = (i * 8 + w) * 64;
    const int slot = slot0 + lane;
    const int r = slot >> 3;
    const int c = (slot & 7) ^ (r & 7);
    srcOff[i] = r * GK + c * 16;
    dstOff[i] = slot0 * 16;  // wave-uniform LDS base
  }

#define STAGE(KT, D)                                                        \
  {                                                                         \
    const int ko = (KT)*BK;                                                 \
    _Pragma("unroll") for (int i = 0; i < 4; ++i)                           \
        gload16(XqB + srcOff[i] + ko, (int8_t*)&lA[(D)][0][0] + dstOff[i]); \
    _Pragma("unroll") for (int i = 0; i < 4; ++i)                           \
        gload16(WtB + srcOff[i] + ko, (int8_t*)&lB[(D)][0][0] + dstOff[i]); \
  }

  // fragment read offsets: A row wr*128+mi*32+l31, k-slice s chunk (2s+kg2)^(row&7)
  int ck[4];
#pragma unroll
  for (int s = 0; s < 4; ++s) ck[s] = ((2 * s + kg2) ^ (l31 & 7)) * 16;

  v16i acc[4][2] = {};
  v4i areg[4][4], breg[2][4];

#define RD_A(MI, D)                                                 \
  {                                                                 \
    const int8_t* p = &lA[(D)][wr * 128 + (MI)*32 + l31][0];        \
    _Pragma("unroll") for (int s = 0; s < 4; ++s)                   \
        areg[MI][s] = *(const v4i*)(p + ck[s]);                     \
  }
#define RD_B(NJ, D)                                                 \
  {                                                                 \
    const int8_t* p = &lB[(D)][wc * 64 + (NJ)*32 + l31][0];         \
    _Pragma("unroll") for (int s = 0; s < 4; ++s)                   \
        breg[NJ][s] = *(const v4i*)(p + ck[s]);                     \
  }

#define MFMA_F(MI, NJ)                                                        \
  _Pragma("unroll") for (int s = 0; s < 4; ++s)                               \
      acc[MI][NJ] = __builtin_amdgcn_mfma_i32_32x32x32_i8(                    \
          areg[MI][s], breg[NJ][s], acc[MI][NJ], 0, 0, 0);

  // prologue: stage tile 0 into buf 0
  STAGE(0, 0);

  for (int kt = 0; kt < NTILES; ++kt) {
    const int d = kt & 1;
    // single rendezvous: my stage-loads of tile kt all returned (vmcnt 0),
    // then barrier => CU-wide: tile kt resident AND all reads of kt-1 done.
    asm volatile("s_waitcnt vmcnt(0)" ::: "memory");
    __builtin_amdgcn_s_barrier();
    if (kt + 1 < NTILES) STAGE(kt + 1, d ^ 1);  // into freed buffer
    // issue all 24 ds_reads, order pinned in 3 groups for exact lgkm gates
    RD_A(0, d);
    RD_A(1, d);
    RD_B(0, d);  // group1: 12 reads
    __builtin_amdgcn_sched_barrier(0);
    RD_B(1, d);  // group2: 4 reads
    __builtin_amdgcn_sched_barrier(0);
    RD_A(2, d);
    RD_A(3, d);  // group3: 8 reads
    __builtin_amdgcn_sched_barrier(0);
    // self-paced MFMA clusters
    asm volatile("s_waitcnt lgkmcnt(12)" ::: "memory");  // group1 done
    __builtin_amdgcn_sched_barrier(0);
    __builtin_amdgcn_s_setprio(1);
    MFMA_F(0, 0);
    MFMA_F(1, 0);
    __builtin_amdgcn_s_setprio(0);
    asm volatile("s_waitcnt lgkmcnt(8)" ::: "memory");  // + group2 done
    __builtin_amdgcn_sched_barrier(0);
    __builtin_amdgcn_s_setprio(1);
    MFMA_F(0, 1);
    MFMA_F(1, 1);
    __builtin_amdgcn_s_setprio(0);
    asm volatile("s_waitcnt lgkmcnt(0)" ::: "memory");  // + group3 done
    __builtin_amdgcn_sched_barrier(0);
    __builtin_amdgcn_s_setprio(1);
    MFMA_F(2, 0);
    MFMA_F(3, 0);
    MFMA_F(2, 1);
    MFMA_F(3, 1);
    __builtin_amdgcn_s_setprio(0);
  }

  // epilogue: dequant + bias -> bf16-round -> f32 store
  // 32x32 C/D: col = lane&31, row = (reg&3) + 8*(reg>>2) + 4*(lane>>5)
#pragma unroll
  for (int nj = 0; nj < 2; ++nj) {
    const int col_l = wc * 64 + nj * 32 + l31;
    const float wsv = wsc[rowB0 + col_l];
    const float bv = bias[rowB0 + col_l];
#pragma unroll
    for (int mi = 0; mi < 4; ++mi) {
#pragma unroll
      for (int r = 0; r < 16; ++r) {
        const size_t row =
            rowA0 + wr * 128 + mi * 32 + (r & 3) + 8 * (r >> 2) + 4 * kg2;
        const float f = (float)acc[mi][nj][r] * xs[row] * wsv + bv;
        C[row * GN + rowB0 + col_l] = __bfloat162float(__float2bfloat16(f));
      }
    }
  }
}

extern "C" void kernel_launch(void* const* d_in, const int* in_sizes, int n_in,
                              void* d_out, int out_size, void* d_ws, size_t ws_size,
                              hipStream_t stream) {
  const int M = GM, K = GK, N = GN;
  const float* x = (const float*)d_in[0];
  const int* W32 = (const int*)d_in[1];  // harness pushes integer inputs as int32
  const float* wsc = (const float*)d_in[2];
  const float* bias = (const float*)d_in[3];
  float* out = (float*)d_out;  // reference output dtype is float32 (bf16-rounded)

  // workspace layout: xs (16KB) | Xq (16MB) | Wt (64MB)
  float* xs = (float*)d_ws;
  int8_t* Xq = (int8_t*)d_ws + 16384;
  int8_t* Wt = (int8_t*)d_ws + 16384 + (size_t)M * K;

  transpose_pack<<<dim3(N / 64, K / 64), 256, 0, stream>>>(W32, Wt, K, N);
  quant_rows<<<M, 256, 0, stream>>>(x, Xq, xs, K);
  gemm_i8<<<dim3((M / BM) * (N / BN)), 512, 0, stream>>>(Xq, Wt, xs, wsc, bias,
                                                         out);
}